// Round 2
// baseline (250.580 us; speedup 1.0000x reference)
//
#include <hip/hip_runtime.h>
#include <cstdint>
#include <cstddef>

#define B_  64
#define D_  128
#define LC_ 1024
#define LQ_ 128
#define NEGV (-1e30f)
#define NINF (-3.402823466e38f)

typedef short s16x8 __attribute__((ext_vector_type(8)));
typedef float f32x4 __attribute__((ext_vector_type(4)));

__device__ __forceinline__ unsigned short f2bf(float x) {
    union { float f; unsigned u; } v; v.f = x;
    unsigned r = v.u + 0x7fffu + ((v.u >> 16) & 1u);   // RNE
    return (unsigned short)(r >> 16);
}

// ---------------------------------------------------------------------------
// kQ: Qt[b][q][d] = bf16(Q[b][d][q]) ; Qb[b][d][q] = bf16(Q) ; sq = sum Q*w_q
// grid (LQ/32, B), 256 thr
// ---------------------------------------------------------------------------
__global__ __launch_bounds__(256) void kQ(const float* __restrict__ Q,
                                          const float* __restrict__ w,
                                          unsigned short* __restrict__ Qt,
                                          unsigned short* __restrict__ Qb,
                                          float* __restrict__ sq_g) {
    __shared__ float tile[32][33];
    __shared__ float wq_l[128];
    __shared__ float red[8][32];
    int t = threadIdx.x;
    int b = blockIdx.y, q0 = blockIdx.x * 32;
    if (t < 128) wq_l[t] = w[t];
    __syncthreads();
    float sqp = 0.f;
    int qq = t & 31, db = t >> 5;
    for (int ch = 0; ch < 4; ch++) {
#pragma unroll
        for (int i = 0; i < 4; i++) {
            int dl = db * 4 + i;
            float v = Q[((size_t)(b * D_ + ch * 32 + dl)) * LQ_ + q0 + qq];
            tile[dl][qq] = v;
            sqp += v * wq_l[ch * 32 + dl];
        }
        __syncthreads();
        {
            int q2 = t >> 3, ds = (t & 7) * 4;
            ushort4 o;
            o.x = f2bf(tile[ds + 0][q2]);
            o.y = f2bf(tile[ds + 1][q2]);
            o.z = f2bf(tile[ds + 2][q2]);
            o.w = f2bf(tile[ds + 3][q2]);
            *(ushort4*)&Qt[((size_t)(b * LQ_ + q0 + q2)) * D_ + ch * 32 + ds] = o;
        }
        {
            int d2 = t >> 3, qs = (t & 7) * 4;
            ushort4 o;
            o.x = f2bf(tile[d2][qs + 0]);
            o.y = f2bf(tile[d2][qs + 1]);
            o.z = f2bf(tile[d2][qs + 2]);
            o.w = f2bf(tile[d2][qs + 3]);
            *(ushort4*)&Qb[((size_t)(b * D_ + ch * 32 + d2)) * LQ_ + q0 + qs] = o;
        }
        __syncthreads();
    }
    red[db][qq] = sqp;
    __syncthreads();
    if (t < 32) {
        float s = 0.f;
#pragma unroll
        for (int j = 0; j < 8; j++) s += red[j][t];
        sq_g[b * LQ_ + q0 + t] = s;
    }
}

// ---------------------------------------------------------------------------
// kS: fused per (b, 128-c-tile):
//   bulk-stage C -> LDS CW[d][c] bf16*wm (XOR-swizzled 8B blocks, (d>>3)&7);
//   S = C^T x Qt via MFMA, A gathered transposed (swizzle -> ~2-way banks);
//   softmax: col stats from raw S first, then exp-overwrite acc (reused for
//   row sum, S1, Tg — saves ~64 v_exp/thread);
//   T2 partial: T2p[tile][b][d][q] = sum_{c in tile} C[d][c] * (S1*g)[c][q]
// grid (LC/128, B), 256 thr
// ---------------------------------------------------------------------------
__global__ __launch_bounds__(256) void kS(const float* __restrict__ C,
                                          const unsigned short* __restrict__ Qt,
                                          const float* __restrict__ w,
                                          const float* __restrict__ sq_g,
                                          const float* __restrict__ cmask,
                                          const float* __restrict__ qmask,
                                          unsigned short* __restrict__ S1b,
                                          float* __restrict__ pmax_g,
                                          float* __restrict__ psum_g,
                                          float* __restrict__ T2p) {
    __shared__ unsigned short CW[128 * 136];   // phase1: [d][c] bf16*wm (swizzled); phase2 reuse: S1 [c][q]
    __shared__ unsigned short Tg[128 * 136];   // [q][c] bf16 = S1*g
    __shared__ float4 red4[8][32];
    __shared__ float wc_l[128], wm_l[128], sq_l[128], cmv_l[128], qmv_l[128], sc_l[128];

    int t = threadIdx.x;
    int b = blockIdx.y, c0 = blockIdx.x * 128;

    // ---- issue all 16 C-tile loads up front (full latency overlap)
    int g = t >> 5, c4 = t & 31;
    float4 v[16];
    {
        const float4* Cb = (const float4*)(C + (size_t)b * D_ * LC_ + c0);
#pragma unroll
        for (int j = 0; j < 16; j++) {
            int d = j * 8 + g;
            v[j] = Cb[(size_t)d * (LC_ / 4) + c4];
        }
    }
    if (t < 128) {
        wc_l[t] = w[D_ + t];
        wm_l[t] = w[2 * D_ + t];
        sq_l[t] = sq_g[b * LQ_ + t];
        cmv_l[t] = (1.0f - cmask[b * LC_ + c0 + t]) * NEGV;
        qmv_l[t] = (1.0f - qmask[b * LQ_ + t]) * NEGV;
    }
    __syncthreads();   // header arrays ready

    // ---- convert + stage [d][c] with 8B-block XOR swizzle; sc partials ----
    {
        float4 scp = {0.f, 0.f, 0.f, 0.f};
#pragma unroll
        for (int j = 0; j < 16; j++) {
            int d = j * 8 + g;
            float wcv = wc_l[d], wmv = wm_l[d];
            scp.x += v[j].x * wcv;
            scp.y += v[j].y * wcv;
            scp.z += v[j].z * wcv;
            scp.w += v[j].w * wcv;
            ushort4 o;
            o.x = f2bf(v[j].x * wmv);
            o.y = f2bf(v[j].y * wmv);
            o.z = f2bf(v[j].z * wmv);
            o.w = f2bf(v[j].w * wmv);
            *(ushort4*)&CW[d * 136 + ((c4 ^ (j & 7)) << 2)] = o;   // (d>>3)&7 == j&7
        }
        red4[g][c4] = scp;
    }
    __syncthreads();   // CW + red4 complete
    if (t < 128) {
        float s = 0.f;
#pragma unroll
        for (int gg = 0; gg < 8; gg++) {
            const float* rp = (const float*)&red4[gg][t >> 2];
            s += rp[t & 3];
        }
        sc_l[t] = s;
    }
    __syncthreads();   // sc_l ready

    // ---- S-MFMA: A gathered transposed from swizzled CW, B from global Qt ----
    int wv = t >> 6, l = t & 63, quad = l >> 4, lp = l & 15;
    int w32 = wv * 32;
    f32x4 zero = {0.f, 0.f, 0.f, 0.f};
    f32x4 acc[2][8];
#pragma unroll
    for (int mc = 0; mc < 2; mc++)
#pragma unroll
        for (int qt = 0; qt < 8; qt++) acc[mc][qt] = zero;

#pragma unroll
    for (int ks = 0; ks < 4; ks++) {
        s16x8 a[2], bb[8];
        int x3 = (ks * 4 + quad) & 7;      // (d>>3)&7 for this ks/quad
#pragma unroll
        for (int mc = 0; mc < 2; mc++) {
            s16x8 av;
            int c = w32 + mc * 16 + lp;
            int cb = ((c >> 2) ^ x3) << 2, clo = c & 3;
#pragma unroll
            for (int e = 0; e < 8; e++)
                av[e] = (short)CW[(ks * 32 + quad * 8 + e) * 136 + cb + clo];
            a[mc] = av;
        }
#pragma unroll
        for (int qt = 0; qt < 8; qt++)
            bb[qt] = *(const s16x8*)&Qt[((size_t)(b * LQ_ + qt * 16 + lp)) * D_ + ks * 32 + quad * 8];
#pragma unroll
        for (int mc = 0; mc < 2; mc++)
#pragma unroll
            for (int qt = 0; qt < 8; qt++)
                acc[mc][qt] = __builtin_amdgcn_mfma_f32_16x16x32_bf16(a[mc], bb[qt], acc[mc][qt], 0, 0, 0);
    }
#pragma unroll
    for (int mc = 0; mc < 2; mc++)
#pragma unroll
        for (int qt = 0; qt < 8; qt++)
#pragma unroll
            for (int i = 0; i < 4; i++)
                acc[mc][qt][i] += sc_l[w32 + mc * 16 + quad * 4 + i] + sq_l[qt * 16 + lp];

    float qmv_r[8];
#pragma unroll
    for (int qt = 0; qt < 8; qt++) qmv_r[qt] = qmv_l[qt * 16 + lp];
    float cmv_r[2][4];
#pragma unroll
    for (int mc = 0; mc < 2; mc++)
#pragma unroll
        for (int i = 0; i < 4; i++) cmv_r[mc][i] = cmv_l[w32 + mc * 16 + quad * 4 + i];

    // ---- (1) row max ----
    float rm_r[2][4];
#pragma unroll
    for (int mc = 0; mc < 2; mc++)
#pragma unroll
        for (int i = 0; i < 4; i++) {
            float m = NINF;
#pragma unroll
            for (int qt = 0; qt < 8; qt++) m = fmaxf(m, acc[mc][qt][i] + qmv_r[qt]);
#pragma unroll
            for (int off = 1; off < 16; off <<= 1) m = fmaxf(m, __shfl_xor(m, off, 64));
            rm_r[mc][i] = m;
        }

    // ---- (2) col partial stats from raw S (before exp-overwrite) ----
    int chunk = blockIdx.x * 4 + wv;
#pragma unroll
    for (int qt = 0; qt < 8; qt++) {
        float cm = NINF;
#pragma unroll
        for (int mc = 0; mc < 2; mc++)
#pragma unroll
            for (int i = 0; i < 4; i++) cm = fmaxf(cm, acc[mc][qt][i] + cmv_r[mc][i]);
        cm = fmaxf(cm, __shfl_xor(cm, 16, 64));
        cm = fmaxf(cm, __shfl_xor(cm, 32, 64));
        float cs = 0.f;
#pragma unroll
        for (int mc = 0; mc < 2; mc++)
#pragma unroll
            for (int i = 0; i < 4; i++) cs += __expf(acc[mc][qt][i] + cmv_r[mc][i] - cm);
        cs += __shfl_xor(cs, 16, 64);
        cs += __shfl_xor(cs, 32, 64);
        if (l < 16) {
            pmax_g[((size_t)(b * 32 + chunk)) * LQ_ + qt * 16 + lp] = cm;
            psum_g[((size_t)(b * 32 + chunk)) * LQ_ + qt * 16 + lp] = cs;
        }
    }

    // ---- (3) exp-overwrite acc + (4) row sum / ri / gs ----
    float ri_r[2][4], gs_r[2][4];
#pragma unroll
    for (int mc = 0; mc < 2; mc++)
#pragma unroll
        for (int i = 0; i < 4; i++) {
            float s = 0.f;
#pragma unroll
            for (int qt = 0; qt < 8; qt++) {
                float e = __expf(acc[mc][qt][i] + qmv_r[qt] - rm_r[mc][i]);
                acc[mc][qt][i] = e;
                s += e;
            }
#pragma unroll
            for (int off = 1; off < 16; off <<= 1) s += __shfl_xor(s, off, 64);
            ri_r[mc][i] = 1.0f / s;
            gs_r[mc][i] = s * __expf(rm_r[mc][i] + cmv_r[mc][i]);
        }

    // ---- (5) S1 -> CW (as [c][q], plain layout); S1*g -> Tg (as [q][c]) ----
    __syncthreads();   // all A-fragment reads of CW are done
#pragma unroll
    for (int mc = 0; mc < 2; mc++)
#pragma unroll
        for (int qt = 0; qt < 8; qt++)
#pragma unroll
            for (int i = 0; i < 4; i++) {
                int row = w32 + mc * 16 + quad * 4 + i;
                int q = qt * 16 + lp;
                float s1 = acc[mc][qt][i] * ri_r[mc][i];
                CW[row * 136 + q] = f2bf(s1);
                Tg[q * 136 + row] = f2bf(s1 * gs_r[mc][i]);
            }
    __syncthreads();

    // ---- S1b copy-out (coalesced) ----
    {
        int row = t >> 1, qh = (t & 1) * 64;
        const uint4* src = (const uint4*)&CW[row * 136 + qh];
        uint4* dst = (uint4*)&S1b[((size_t)(b * LC_ + c0 + row)) * LQ_ + qh];
#pragma unroll
        for (int j = 0; j < 8; j++) dst[j] = src[j];
    }

    // ---- T2 partial GEMM: A = C (fp32->bf16 direct, L2-hot re-read), B = Tg ----
    f32x4 acc2[2][8];
#pragma unroll
    for (int mc = 0; mc < 2; mc++)
#pragma unroll
        for (int nt = 0; nt < 8; nt++) acc2[mc][nt] = zero;
#pragma unroll
    for (int ks = 0; ks < 4; ks++) {
        s16x8 a2[2], bb[8];
#pragma unroll
        for (int m = 0; m < 2; m++) {
            int d = w32 + m * 16 + lp;
            const float4* p = (const float4*)&C[((size_t)(b * D_ + d)) * LC_ + c0 + ks * 32 + quad * 8];
            float4 v0 = p[0], v1 = p[1];
            unsigned short* pp = (unsigned short*)&a2[m];
            pp[0] = f2bf(v0.x); pp[1] = f2bf(v0.y); pp[2] = f2bf(v0.z); pp[3] = f2bf(v0.w);
            pp[4] = f2bf(v1.x); pp[5] = f2bf(v1.y); pp[6] = f2bf(v1.z); pp[7] = f2bf(v1.w);
        }
#pragma unroll
        for (int nt = 0; nt < 8; nt++)
            bb[nt] = *(const s16x8*)&Tg[(nt * 16 + lp) * 136 + ks * 32 + quad * 8];
#pragma unroll
        for (int m = 0; m < 2; m++)
#pragma unroll
            for (int nt = 0; nt < 8; nt++)
                acc2[m][nt] = __builtin_amdgcn_mfma_f32_16x16x32_bf16(a2[m], bb[nt], acc2[m][nt], 0, 0, 0);
    }
    size_t base = ((size_t)(blockIdx.x * B_ + b)) * ((size_t)D_ * LQ_);
#pragma unroll
    for (int mc = 0; mc < 2; mc++)
#pragma unroll
        for (int i = 0; i < 4; i++) {
            int d = w32 + mc * 16 + quad * 4 + i;
#pragma unroll
            for (int nt = 0; nt < 8; nt++)
                T2p[base + (size_t)d * LQ_ + nt * 16 + lp] = acc2[mc][nt][i];
        }
}

// ---------------------------------------------------------------------------
// k2b: reduce 32 col-partial chunks -> hq = exp(-colmax), ci = 1/colsum
// ---------------------------------------------------------------------------
__global__ __launch_bounds__(128) void k2b(const float* __restrict__ pmax,
                                           const float* __restrict__ psum,
                                           float* __restrict__ hq_g,
                                           float* __restrict__ ci_g) {
    int q = threadIdx.x, b = blockIdx.x;
    float m = NINF;
    for (int j = 0; j < 32; j++) m = fmaxf(m, pmax[((size_t)(b * 32 + j)) * LQ_ + q]);
    float s = 0.f;
    for (int j = 0; j < 32; j++)
        s += psum[((size_t)(b * 32 + j)) * LQ_ + q] * __expf(pmax[((size_t)(b * 32 + j)) * LQ_ + q] - m);
    hq_g[b * LQ_ + q] = __expf(-m);
    ci_g[b * LQ_ + q] = 1.0f / s;
}

// ---------------------------------------------------------------------------
// k3b: T2b bf16 = (sum of 8 c-tile partials) * hq[q] * ci[q]
// ---------------------------------------------------------------------------
__global__ __launch_bounds__(256) void k3b(const float* __restrict__ T2p,
                                           const float* __restrict__ hq_g,
                                           const float* __restrict__ ci_g,
                                           unsigned short* __restrict__ T2b) {
    int idx = blockIdx.x * 256 + threadIdx.x;
    const size_t N = (size_t)B_ * D_ * LQ_;
    int b = idx >> 14, q = idx & 127;
    float s = 0.f;
#pragma unroll
    for (int j = 0; j < 8; j++) s += T2p[(size_t)j * N + idx];
    T2b[idx] = f2bf(s * hq_g[b * LQ_ + q] * ci_g[b * LQ_ + q]);
}

// ---------------------------------------------------------------------------
// kC_out (swapped operands): acc[row=c][col=d]; A = S1b rows c, B = Qb/T2b
// cols d, contraction over q. Each lane's 4 acc elements = 4 consecutive c of
// one d-row -> float4 C loads + float4 stores for all 4 output streams.
// VMEM instrs/thread: 192 -> ~108 (68 frag loads + 8 C loads + 32 stores).
// grid (LC/64, B), 256 thr
// ---------------------------------------------------------------------------
__global__ __launch_bounds__(256) void kC_out(const float* __restrict__ C,
                                              const unsigned short* __restrict__ Qb,
                                              const unsigned short* __restrict__ T2b,
                                              const unsigned short* __restrict__ S1b,
                                              float* __restrict__ out) {
    int t = threadIdx.x;
    int b = blockIdx.y, c0 = blockIdx.x * 64;
    int wv = t >> 6, l = t & 63, quad = l >> 4, lp = l & 15;
    int cw = c0 + wv * 16;                 // this wave's 16 c-rows
    f32x4 zero = {0.f, 0.f, 0.f, 0.f};
    f32x4 accA[8], accB[8];
#pragma unroll
    for (int nt = 0; nt < 8; nt++) { accA[nt] = zero; accB[nt] = zero; }

#pragma unroll
    for (int ks = 0; ks < 4; ks++) {
        s16x8 a = *(const s16x8*)&S1b[((size_t)(b * LC_ + cw + lp)) * LQ_ + ks * 32 + quad * 8];
        s16x8 bq[8], bt[8];
#pragma unroll
        for (int nt = 0; nt < 8; nt++) {
            bq[nt] = *(const s16x8*)&Qb[((size_t)(b * D_ + nt * 16 + lp)) * LQ_ + ks * 32 + quad * 8];
            bt[nt] = *(const s16x8*)&T2b[((size_t)(b * D_ + nt * 16 + lp)) * LQ_ + ks * 32 + quad * 8];
        }
#pragma unroll
        for (int nt = 0; nt < 8; nt++) {
            accA[nt] = __builtin_amdgcn_mfma_f32_16x16x32_bf16(a, bq[nt], accA[nt], 0, 0, 0);
            accB[nt] = __builtin_amdgcn_mfma_f32_16x16x32_bf16(a, bt[nt], accB[nt], 0, 0, 0);
        }
    }
    const size_t DL = (size_t)D_ * LC_;
    int cc = cw + quad * 4;                // 4 consecutive c per lane
#pragma unroll
    for (int nt = 0; nt < 8; nt++) {
        int d = nt * 16 + lp;
        const f32x4 cv = *(const f32x4*)&C[((size_t)(b * D_ + d)) * LC_ + cc];
        f32x4 av = accA[nt], bv = accB[nt];
        f32x4 ca = cv * av, cb = cv * bv;
        size_t ob = ((size_t)(b * 4 * D_ + d)) * LC_ + cc;
        *(f32x4*)&out[ob] = cv;
        *(f32x4*)&out[ob + DL] = av;
        *(f32x4*)&out[ob + 2 * DL] = ca;
        *(f32x4*)&out[ob + 3 * DL] = cb;
    }
}

// ---------------------------------------------------------------------------
extern "C" void kernel_launch(void* const* d_in, const int* in_sizes, int n_in,
                              void* d_out, int out_size, void* d_ws, size_t ws_size,
                              hipStream_t stream) {
    const float* C     = (const float*)d_in[0];
    const float* Q     = (const float*)d_in[1];
    const float* cmask = (const float*)d_in[2];
    const float* qmask = (const float*)d_in[3];
    const float* w     = (const float*)d_in[4];
    float* out = (float*)d_out;

    unsigned short* us = (unsigned short*)d_ws;
    unsigned short* S1b = us;                                   // B*LC*LQ
    unsigned short* Qt  = S1b + (size_t)B_ * LC_ * LQ_;         // B*LQ*D
    unsigned short* Qb  = Qt  + (size_t)B_ * LQ_ * D_;          // B*D*LQ
    unsigned short* T2b = Qb  + (size_t)B_ * D_ * LQ_;          // B*D*LQ
    float* fp = (float*)(T2b + (size_t)B_ * D_ * LQ_);
    float* T2p    = fp;                                         // 8*B*D*LQ
    float* pmax_g = T2p + (size_t)8 * B_ * D_ * LQ_;            // B*32*LQ
    float* psum_g = pmax_g + (size_t)B_ * 32 * LQ_;             // B*32*LQ
    float* sq_g   = psum_g + (size_t)B_ * 32 * LQ_;             // B*LQ
    float* hq_g   = sq_g + (size_t)B_ * LQ_;                    // B*LQ
    float* ci_g   = hq_g + (size_t)B_ * LQ_;                    // B*LQ

    kQ<<<dim3(LQ_ / 32, B_), 256, 0, stream>>>(Q, w, Qt, Qb, sq_g);
    kS<<<dim3(LC_ / 128, B_), 256, 0, stream>>>(C, Qt, w, sq_g, cmask, qmask,
                                                S1b, pmax_g, psum_g, T2p);
    k2b<<<dim3(B_), 128, 0, stream>>>(pmax_g, psum_g, hq_g, ci_g);
    k3b<<<dim3(B_ * D_ * LQ_ / 256), 256, 0, stream>>>(T2p, hq_g, ci_g, T2b);
    kC_out<<<dim3(LC_ / 64, B_), 256, 0, stream>>>(C, Qb, T2b, S1b, out);
}

// Round 4
// 219.146 us; speedup vs baseline: 1.1434x; 1.1434x over previous
//
#include <hip/hip_runtime.h>
#include <cstdint>
#include <cstddef>

#define B_  64
#define D_  128
#define LC_ 1024
#define LQ_ 128
#define NEGV (-1e30f)
#define NINF (-3.402823466e38f)

typedef short s16x8 __attribute__((ext_vector_type(8)));
typedef float f32x4 __attribute__((ext_vector_type(4)));

__device__ __forceinline__ unsigned short f2bf(float x) {
    union { float f; unsigned u; } v; v.f = x;
    unsigned r = v.u + 0x7fffu + ((v.u >> 16) & 1u);   // RNE
    return (unsigned short)(r >> 16);
}

// ---------------------------------------------------------------------------
// k1: per (b, 128-c-tile) block, 256 thr, 2 blocks/CU:
//   - redundant Q[b] transpose -> QT LDS [q][d] bf16 (+ sq_l local)
//   - stage C -> CW [d][c] bf16*wm (XOR-swizzled), sc partials
//   - S-MFMA (A from CW transposed-gather, B from QT LDS)
//   - softmax row stats + col partial stats (pmax/psum -> global)
//   - S1 -> S1b global; S1*g -> Tg LDS (QT region reused)
//   - T2 partial GEMM -> T2p global
// grid (LC/128, B)
// ---------------------------------------------------------------------------
__global__ __launch_bounds__(256, 2) void k1(const float* __restrict__ C,
                                             const float* __restrict__ Q,
                                             const float* __restrict__ cmask,
                                             const float* __restrict__ qmask,
                                             const float* __restrict__ w,
                                             unsigned short* __restrict__ S1b,
                                             float* __restrict__ pmax_g,
                                             float* __restrict__ psum_g,
                                             float* __restrict__ T2p) {
    __shared__ unsigned short CW[128 * 136];   // Q-stage fp32 scratch -> [d][c] bf16*wm -> S1 [c][q]
    __shared__ unsigned short QT[128 * 136];   // Qt [q][d] bf16 -> later Tg [q][c]
    __shared__ float4 red4[8][32];             // wq_l (fp32[128]) first, then sc partials
    __shared__ float wc_l[128], wm_l[128], cmv_l[128], qmv_l[128], sc_l[128], sq_l[128];

    int t = threadIdx.x;
    int b = blockIdx.y, ct = blockIdx.x, c0 = ct * 128;
    int g = t >> 5, c4 = t & 31;

    // ---- issue all 16 C-tile loads up front (hidden under Q phase) ----
    float4 v[16];
    {
        const float4* Cb = (const float4*)(C + (size_t)b * D_ * LC_ + c0);
#pragma unroll
        for (int j = 0; j < 16; j++) {
            int d = j * 8 + g;
            v[j] = Cb[(size_t)d * (LC_ / 4) + c4];
        }
    }
    float* wq_l = (float*)red4;
    if (t < 128) {
        wq_l[t] = w[t];
        wc_l[t] = w[D_ + t];
        wm_l[t] = w[2 * D_ + t];
        cmv_l[t] = (1.0f - cmask[b * LC_ + c0 + t]) * NEGV;
        qmv_l[t] = (1.0f - qmask[b * LQ_ + t]) * NEGV;
    }
    __syncthreads();

    // ---- Q[b] transpose -> QT [q][136] bf16; sq_l = sum_d Q*wq ----
    {
        float* CWf = (float*)CW;               // [64][132] fp32 scratch
        int qq = t >> 1, ph = t & 1;
        float sqv = 0.f;
#pragma unroll
        for (int h = 0; h < 2; h++) {
#pragma unroll
            for (int j = 0; j < 8; j++) {
                int idx = j * 256 + t;
                int r = idx >> 5, cc = idx & 31;
                float4 qv = *(const float4*)&Q[((size_t)(b * D_ + h * 64 + r)) * LQ_ + cc * 4];
                *(float4*)&CWf[r * 132 + cc * 4] = qv;
            }
            __syncthreads();
            unsigned short u[32];
#pragma unroll
            for (int k = 0; k < 32; k++) {
                float val = CWf[(ph * 32 + k) * 132 + qq];
                sqv += val * wq_l[h * 64 + ph * 32 + k];
                u[k] = f2bf(val);
            }
#pragma unroll
            for (int k4 = 0; k4 < 8; k4++) {
                ushort4 o;
                o.x = u[k4 * 4 + 0]; o.y = u[k4 * 4 + 1];
                o.z = u[k4 * 4 + 2]; o.w = u[k4 * 4 + 3];
                *(ushort4*)&QT[qq * 136 + h * 64 + ph * 32 + k4 * 4] = o;
            }
            __syncthreads();
        }
        sqv += __shfl_xor(sqv, 1, 64);
        if (ph == 0) sq_l[qq] = sqv;
    }

    // ---- convert + stage C -> CW [d][c] with 8B-block XOR swizzle; sc ----
    {
        float4 scp = {0.f, 0.f, 0.f, 0.f};
#pragma unroll
        for (int j = 0; j < 16; j++) {
            int d = j * 8 + g;
            float wcv = wc_l[d], wmv = wm_l[d];
            scp.x += v[j].x * wcv;
            scp.y += v[j].y * wcv;
            scp.z += v[j].z * wcv;
            scp.w += v[j].w * wcv;
            ushort4 o;
            o.x = f2bf(v[j].x * wmv);
            o.y = f2bf(v[j].y * wmv);
            o.z = f2bf(v[j].z * wmv);
            o.w = f2bf(v[j].w * wmv);
            *(ushort4*)&CW[d * 136 + ((c4 ^ (j & 7)) << 2)] = o;   // (d>>3)&7 == j&7
        }
        red4[g][c4] = scp;
    }
    __syncthreads();
    if (t < 128) {
        float s = 0.f;
#pragma unroll
        for (int gg = 0; gg < 8; gg++) {
            const float* rp = (const float*)&red4[gg][t >> 2];
            s += rp[t & 3];
        }
        sc_l[t] = s;
    }
    __syncthreads();

    // ---- S-MFMA: A gathered transposed from swizzled CW, B from QT LDS ----
    int wv = t >> 6, l = t & 63, quad = l >> 4, lp = l & 15;
    int w32 = wv * 32;
    f32x4 zero = {0.f, 0.f, 0.f, 0.f};
    f32x4 acc[2][8];
#pragma unroll
    for (int mc = 0; mc < 2; mc++)
#pragma unroll
        for (int qt = 0; qt < 8; qt++) acc[mc][qt] = zero;

#pragma unroll
    for (int ks = 0; ks < 4; ks++) {
        s16x8 a[2], bb[8];
        int x3 = (ks * 4 + quad) & 7;
#pragma unroll
        for (int mc = 0; mc < 2; mc++) {
            s16x8 av;
            int c = w32 + mc * 16 + lp;
            int cb = ((c >> 2) ^ x3) << 2, clo = c & 3;
#pragma unroll
            for (int e = 0; e < 8; e++)
                av[e] = (short)CW[(ks * 32 + quad * 8 + e) * 136 + cb + clo];
            a[mc] = av;
        }
#pragma unroll
        for (int qt = 0; qt < 8; qt++)
            bb[qt] = *(const s16x8*)&QT[(qt * 16 + lp) * 136 + ks * 32 + quad * 8];
#pragma unroll
        for (int mc = 0; mc < 2; mc++)
#pragma unroll
            for (int qt = 0; qt < 8; qt++)
                acc[mc][qt] = __builtin_amdgcn_mfma_f32_16x16x32_bf16(a[mc], bb[qt], acc[mc][qt], 0, 0, 0);
    }
#pragma unroll
    for (int mc = 0; mc < 2; mc++)
#pragma unroll
        for (int qt = 0; qt < 8; qt++)
#pragma unroll
            for (int i = 0; i < 4; i++)
                acc[mc][qt][i] += sc_l[w32 + mc * 16 + quad * 4 + i] + sq_l[qt * 16 + lp];

    float qmv_r[8];
#pragma unroll
    for (int qt = 0; qt < 8; qt++) qmv_r[qt] = qmv_l[qt * 16 + lp];
    float cmv_r[2][4];
#pragma unroll
    for (int mc = 0; mc < 2; mc++)
#pragma unroll
        for (int i = 0; i < 4; i++) cmv_r[mc][i] = cmv_l[w32 + mc * 16 + quad * 4 + i];

    // ---- (1) row max ----
    float rm_r[2][4];
#pragma unroll
    for (int mc = 0; mc < 2; mc++)
#pragma unroll
        for (int i = 0; i < 4; i++) {
            float m = NINF;
#pragma unroll
            for (int qt = 0; qt < 8; qt++) m = fmaxf(m, acc[mc][qt][i] + qmv_r[qt]);
#pragma unroll
            for (int off = 1; off < 16; off <<= 1) m = fmaxf(m, __shfl_xor(m, off, 64));
            rm_r[mc][i] = m;
        }

    // ---- (2) col partial stats from raw S ----
    int chunk = ct * 4 + wv;
#pragma unroll
    for (int qt = 0; qt < 8; qt++) {
        float cm = NINF;
#pragma unroll
        for (int mc = 0; mc < 2; mc++)
#pragma unroll
            for (int i = 0; i < 4; i++) cm = fmaxf(cm, acc[mc][qt][i] + cmv_r[mc][i]);
        cm = fmaxf(cm, __shfl_xor(cm, 16, 64));
        cm = fmaxf(cm, __shfl_xor(cm, 32, 64));
        float cs = 0.f;
#pragma unroll
        for (int mc = 0; mc < 2; mc++)
#pragma unroll
            for (int i = 0; i < 4; i++) cs += __expf(acc[mc][qt][i] + cmv_r[mc][i] - cm);
        cs += __shfl_xor(cs, 16, 64);
        cs += __shfl_xor(cs, 32, 64);
        if (l < 16) {
            pmax_g[((size_t)(b * 32 + chunk)) * LQ_ + qt * 16 + lp] = cm;
            psum_g[((size_t)(b * 32 + chunk)) * LQ_ + qt * 16 + lp] = cs;
        }
    }

    // ---- (3) exp-overwrite acc + (4) row sum / ri / gs ----
    float ri_r[2][4], gs_r[2][4];
#pragma unroll
    for (int mc = 0; mc < 2; mc++)
#pragma unroll
        for (int i = 0; i < 4; i++) {
            float s = 0.f;
#pragma unroll
            for (int qt = 0; qt < 8; qt++) {
                float e = __expf(acc[mc][qt][i] + qmv_r[qt] - rm_r[mc][i]);
                acc[mc][qt][i] = e;
                s += e;
            }
#pragma unroll
            for (int off = 1; off < 16; off <<= 1) s += __shfl_xor(s, off, 64);
            ri_r[mc][i] = 1.0f / s;
            gs_r[mc][i] = s * __expf(rm_r[mc][i] + cmv_r[mc][i]);
        }

    // ---- (5) S1 -> CW [c][q] plain; S1*g -> Tg (QT region) [q][c] ----
    __syncthreads();   // all CW/QT fragment reads done
#pragma unroll
    for (int mc = 0; mc < 2; mc++)
#pragma unroll
        for (int qt = 0; qt < 8; qt++)
#pragma unroll
            for (int i = 0; i < 4; i++) {
                int row = w32 + mc * 16 + quad * 4 + i;
                int q = qt * 16 + lp;
                float s1 = acc[mc][qt][i] * ri_r[mc][i];
                CW[row * 136 + q] = f2bf(s1);
                QT[q * 136 + row] = f2bf(s1 * gs_r[mc][i]);
            }
    __syncthreads();

    // ---- S1b copy-out (coalesced) ----
    {
        int row = t >> 1, qh = (t & 1) * 64;
        const uint4* src = (const uint4*)&CW[row * 136 + qh];
        uint4* dst = (uint4*)&S1b[((size_t)(b * LC_ + c0 + row)) * LQ_ + qh];
#pragma unroll
        for (int j = 0; j < 8; j++) dst[j] = src[j];
    }

    // ---- T2 partial GEMM: A = C (fp32->bf16, L2-hot re-read), B = Tg ----
    f32x4 acc2[2][8];
#pragma unroll
    for (int mc = 0; mc < 2; mc++)
#pragma unroll
        for (int nt = 0; nt < 8; nt++) acc2[mc][nt] = zero;
#pragma unroll
    for (int ks = 0; ks < 4; ks++) {
        s16x8 a2[2], bb[8];
#pragma unroll
        for (int m = 0; m < 2; m++) {
            int d = w32 + m * 16 + lp;
            const float4* p = (const float4*)&C[((size_t)(b * D_ + d)) * LC_ + c0 + ks * 32 + quad * 8];
            float4 v0 = p[0], v1 = p[1];
            unsigned short* pp = (unsigned short*)&a2[m];
            pp[0] = f2bf(v0.x); pp[1] = f2bf(v0.y); pp[2] = f2bf(v0.z); pp[3] = f2bf(v0.w);
            pp[4] = f2bf(v1.x); pp[5] = f2bf(v1.y); pp[6] = f2bf(v1.z); pp[7] = f2bf(v1.w);
        }
#pragma unroll
        for (int nt = 0; nt < 8; nt++)
            bb[nt] = *(const s16x8*)&QT[(nt * 16 + lp) * 136 + ks * 32 + quad * 8];
#pragma unroll
        for (int m = 0; m < 2; m++)
#pragma unroll
            for (int nt = 0; nt < 8; nt++)
                acc2[m][nt] = __builtin_amdgcn_mfma_f32_16x16x32_bf16(a2[m], bb[nt], acc2[m][nt], 0, 0, 0);
    }
    size_t base = ((size_t)(ct * B_ + b)) * ((size_t)D_ * LQ_);
#pragma unroll
    for (int mc = 0; mc < 2; mc++)
#pragma unroll
        for (int i = 0; i < 4; i++) {
            int d = w32 + mc * 16 + quad * 4 + i;
#pragma unroll
            for (int nt = 0; nt < 8; nt++)
                T2p[base + (size_t)d * LQ_ + nt * 16 + lp] = acc2[mc][nt][i];
        }
}

// ---------------------------------------------------------------------------
// k2: per (b, d-chunk of 16): softmax-2 scale (redundant, L2-hot) +
//     T2p 8-tile reduce -> T2b bf16.  grid (B*8), 256 thr
// ---------------------------------------------------------------------------
__global__ __launch_bounds__(256) void k2(const float* __restrict__ pmax_g,
                                          const float* __restrict__ psum_g,
                                          const float* __restrict__ T2p,
                                          unsigned short* __restrict__ T2b) {
    __shared__ float scale_l[128];
    int t = threadIdx.x;
    int bid = blockIdx.x;
    int b = bid >> 3, dc = bid & 7;
    if (t < 128) {
        float m = NINF;
        for (int j = 0; j < 32; j++)
            m = fmaxf(m, pmax_g[((size_t)(b * 32 + j)) * LQ_ + t]);
        float s = 0.f;
        for (int j = 0; j < 32; j++)
            s += psum_g[((size_t)(b * 32 + j)) * LQ_ + t] *
                 __expf(pmax_g[((size_t)(b * 32 + j)) * LQ_ + t] - m);
        scale_l[t] = __expf(-m) / s;
    }
    __syncthreads();
    int d = dc * 16 + (t >> 4), q8 = (t & 15) * 8;
    float a8[8] = {0.f, 0.f, 0.f, 0.f, 0.f, 0.f, 0.f, 0.f};
#pragma unroll
    for (int j = 0; j < 8; j++) {
        const float* p = &T2p[(((size_t)j * B_ + b) * D_ + d) * LQ_ + q8];
        float4 x0 = *(const float4*)p, x1 = *(const float4*)(p + 4);
        a8[0] += x0.x; a8[1] += x0.y; a8[2] += x0.z; a8[3] += x0.w;
        a8[4] += x1.x; a8[5] += x1.y; a8[6] += x1.z; a8[7] += x1.w;
    }
    ushort4 o0, o1;
    o0.x = f2bf(a8[0] * scale_l[q8 + 0]);
    o0.y = f2bf(a8[1] * scale_l[q8 + 1]);
    o0.z = f2bf(a8[2] * scale_l[q8 + 2]);
    o0.w = f2bf(a8[3] * scale_l[q8 + 3]);
    o1.x = f2bf(a8[4] * scale_l[q8 + 4]);
    o1.y = f2bf(a8[5] * scale_l[q8 + 5]);
    o1.z = f2bf(a8[6] * scale_l[q8 + 6]);
    o1.w = f2bf(a8[7] * scale_l[q8 + 7]);
    size_t tb = ((size_t)(b * D_ + d)) * LQ_ + q8;
    *(ushort4*)&T2b[tb] = o0;
    *(ushort4*)&T2b[tb + 4] = o1;
}

// ---------------------------------------------------------------------------
// k3: output GEMMs. A-fragments: Q fp32 direct-convert (kills Qb) + T2b bf16;
//     B-fragments: S1b global.  Epilogue: C re-read + 4-stream stores.
// grid (LC/128, B), 256 thr
// ---------------------------------------------------------------------------
__global__ __launch_bounds__(256) void k3(const float* __restrict__ C,
                                          const float* __restrict__ Q,
                                          const unsigned short* __restrict__ T2b,
                                          const unsigned short* __restrict__ S1b,
                                          float* __restrict__ out) {
    int t = threadIdx.x;
    int b = blockIdx.y, c0 = blockIdx.x * 128;
    int wv = t >> 6, l = t & 63, quad = l >> 4, lp = l & 15;
    int w32 = wv * 32;
    f32x4 zero = {0.f, 0.f, 0.f, 0.f};
    f32x4 accA[2][8], accB[2][8];
#pragma unroll
    for (int mc = 0; mc < 2; mc++)
#pragma unroll
        for (int nt = 0; nt < 8; nt++) { accA[mc][nt] = zero; accB[mc][nt] = zero; }

#pragma unroll
    for (int ks = 0; ks < 4; ks++) {
        s16x8 aq[2], at[2], bb[8];
#pragma unroll
        for (int mc = 0; mc < 2; mc++) {
            int d = w32 + mc * 16 + lp;
            const float4* p = (const float4*)&Q[((size_t)(b * D_ + d)) * LQ_ + ks * 32 + quad * 8];
            float4 v0 = p[0], v1 = p[1];
            unsigned short* pp = (unsigned short*)&aq[mc];
            pp[0] = f2bf(v0.x); pp[1] = f2bf(v0.y); pp[2] = f2bf(v0.z); pp[3] = f2bf(v0.w);
            pp[4] = f2bf(v1.x); pp[5] = f2bf(v1.y); pp[6] = f2bf(v1.z); pp[7] = f2bf(v1.w);
            at[mc] = *(const s16x8*)&T2b[((size_t)(b * D_ + d)) * LQ_ + ks * 32 + quad * 8];
        }
#pragma unroll
        for (int nt = 0; nt < 8; nt++)
            bb[nt] = *(const s16x8*)&S1b[((size_t)(b * LC_ + c0 + nt * 16 + lp)) * LQ_ + ks * 32 + quad * 8];
#pragma unroll
        for (int mc = 0; mc < 2; mc++)
#pragma unroll
            for (int nt = 0; nt < 8; nt++) {
                accA[mc][nt] = __builtin_amdgcn_mfma_f32_16x16x32_bf16(aq[mc], bb[nt], accA[mc][nt], 0, 0, 0);
                accB[mc][nt] = __builtin_amdgcn_mfma_f32_16x16x32_bf16(at[mc], bb[nt], accB[mc][nt], 0, 0, 0);
            }
    }
    const size_t DL = (size_t)D_ * LC_;
#pragma unroll
    for (int mc = 0; mc < 2; mc++)
#pragma unroll
        for (int i = 0; i < 4; i++) {
            int d = w32 + mc * 16 + quad * 4 + i;
            const float* Crow = C + ((size_t)(b * D_ + d)) * LC_ + c0;
            size_t ob = ((size_t)(b * 4 * D_ + d)) * LC_ + c0;
#pragma unroll
            for (int nt = 0; nt < 8; nt++) {
                int c = nt * 16 + lp;
                float cv = Crow[c];
                float a = accA[mc][nt][i];
                float bt = accB[mc][nt][i];
                out[ob + c] = cv;
                out[ob + DL + c] = a;
                out[ob + 2 * DL + c] = cv * a;
                out[ob + 3 * DL + c] = cv * bt;
            }
        }
}

// ---------------------------------------------------------------------------
extern "C" void kernel_launch(void* const* d_in, const int* in_sizes, int n_in,
                              void* d_out, int out_size, void* d_ws, size_t ws_size,
                              hipStream_t stream) {
    const float* C     = (const float*)d_in[0];
    const float* Q     = (const float*)d_in[1];
    const float* cmask = (const float*)d_in[2];
    const float* qmask = (const float*)d_in[3];
    const float* w     = (const float*)d_in[4];
    float* out = (float*)d_out;

    unsigned short* us = (unsigned short*)d_ws;
    unsigned short* S1b = us;                                   // B*LC*LQ
    unsigned short* T2b = S1b + (size_t)B_ * LC_ * LQ_;         // B*D*LQ
    float* fp = (float*)(T2b + (size_t)B_ * D_ * LQ_);
    float* T2p    = fp;                                         // 8*B*D*LQ
    float* pmax_g = T2p + (size_t)8 * B_ * D_ * LQ_;            // B*32*LQ
    float* psum_g = pmax_g + (size_t)B_ * 32 * LQ_;             // B*32*LQ

    k1<<<dim3(LC_ / 128, B_), 256, 0, stream>>>(C, Q, cmask, qmask, w,
                                                S1b, pmax_g, psum_g, T2p);
    k2<<<dim3(B_ * 8), 256, 0, stream>>>(pmax_g, psum_g, T2p, T2b);
    k3<<<dim3(LC_ / 128, B_), 256, 0, stream>>>(C, Q, T2b, S1b, out);
}